// Round 7
// baseline (156.095 us; speedup 1.0000x reference)
//
#include <hip/hip_runtime.h>

// DeepComplexRBF as 6 plain kernels in the captured graph (one per phase).
//   dist_sq[i] = sum_j |y[j] - G[i,j]|^2 ; phi[i] = exp(-dist_sq/(2 s[i]))
//   y_new[o]   = sum_i W[o,i]*phi[i] + b[o]
// 576 MB of G/W streamed once; ~280 MB served by L3 across graph replays.
//
// Round-6 (119.3 us) -> round-7 change: occupancy 16 -> 32 waves/CU.
// Half-row per wave: 512-thr blocks (8 waves), 4 rows/block, wave w owns
// row 4b+(w>>1), column half (w&1). Two-pass inner (re plane, then im
// plane) keeps live set at 8 float4 so __launch_bounds__(512,8) fits
// VGPR<=64 without spill -> 4 blocks/CU = 32 waves/CU. One LDS
// pair-combine per kernel. Shared vectors (y 32KB, phi 16KB) read
// per-lane through L1 (no LDS staging - beat LDS version in r6 vs r1).

#define D0 1024
#define H  4096

__device__ __forceinline__ float wave_sum(float v) {
#pragma unroll
    for (int off = 32; off > 0; off >>= 1) v += __shfl_down(v, off, 64);
    return v;
}

// phi[row] = exp(-|y - G[row]|^2 / (2 s[row])); G is (2, ROWS, COLS).
// Grid: ROWS/4 blocks x 512 threads.
template <int COLS, int ROWS>
__global__ __launch_bounds__(512, 8) void phi_k(
        const float* __restrict__ G,
        const float* __restrict__ yre, const float* __restrict__ yim,
        const float* __restrict__ sv, float* __restrict__ phi) {
    const int lane = threadIdx.x & 63;
    const int w = threadIdx.x >> 6;            // 0..7
    const int row = blockIdx.x * 4 + (w >> 1);
    const int half = w & 1;
    constexpr int L = COLS / 2;                // cols per wave
    constexpr int NIT = L / 256;               // float4 steps per lane
    constexpr int B = (NIT < 4) ? NIT : 4;     // burst width

    const float* gre = G + (size_t)row * COLS + half * L;
    const float* gim = gre + (size_t)ROWS * COLS;
    const float* yr0 = yre + half * L;
    const float* yi0 = yim + half * L;

    float acc = 0.f;
    // pass 1: real plane
#pragma unroll
    for (int it0 = 0; it0 < NIT; it0 += B) {
        float4 g[B], y[B];
#pragma unroll
        for (int u = 0; u < B; ++u) {
            const int j = lane * 4 + (it0 + u) * 256;
            g[u] = *(const float4*)(gre + j);
            y[u] = *(const float4*)(yr0 + j);
        }
#pragma unroll
        for (int u = 0; u < B; ++u) {
            float d;
            d = y[u].x - g[u].x; acc += d * d;
            d = y[u].y - g[u].y; acc += d * d;
            d = y[u].z - g[u].z; acc += d * d;
            d = y[u].w - g[u].w; acc += d * d;
        }
    }
    // pass 2: imag plane
#pragma unroll
    for (int it0 = 0; it0 < NIT; it0 += B) {
        float4 g[B], y[B];
#pragma unroll
        for (int u = 0; u < B; ++u) {
            const int j = lane * 4 + (it0 + u) * 256;
            g[u] = *(const float4*)(gim + j);
            y[u] = *(const float4*)(yi0 + j);
        }
#pragma unroll
        for (int u = 0; u < B; ++u) {
            float d;
            d = y[u].x - g[u].x; acc += d * d;
            d = y[u].y - g[u].y; acc += d * d;
            d = y[u].z - g[u].z; acc += d * d;
            d = y[u].w - g[u].w; acc += d * d;
        }
    }

    acc = wave_sum(acc);
    __shared__ float sred[8];
    if (lane == 0) sred[w] = acc;
    __syncthreads();
    if (threadIdx.x < 4) {
        const int r = blockIdx.x * 4 + threadIdx.x;
        const float d = sred[2 * threadIdx.x] + sred[2 * threadIdx.x + 1];
        phi[r] = expf(-d / (2.0f * sv[r]));
    }
}

// (ore,oim)[row] = W[row] . phi + b[row]; W is (2, ROWS, COLS), bias (2, ROWS).
// Grid: ROWS/4 blocks x 512 threads.
template <int COLS, int ROWS>
__global__ __launch_bounds__(512, 8) void w_k(
        const float* __restrict__ W, const float* __restrict__ bias,
        const float* __restrict__ phi,
        float* __restrict__ ore, float* __restrict__ oim) {
    const int lane = threadIdx.x & 63;
    const int w = threadIdx.x >> 6;
    const int row = blockIdx.x * 4 + (w >> 1);
    const int half = w & 1;
    constexpr int L = COLS / 2;
    constexpr int NIT = L / 256;
    constexpr int B = (NIT < 4) ? NIT : 4;

    const float* wre = W + (size_t)row * COLS + half * L;
    const float* wim = wre + (size_t)ROWS * COLS;
    const float* ph0 = phi + half * L;

    float ar = 0.f, ai = 0.f;
    // pass 1: real plane
#pragma unroll
    for (int it0 = 0; it0 < NIT; it0 += B) {
        float4 m[B], p[B];
#pragma unroll
        for (int u = 0; u < B; ++u) {
            const int j = lane * 4 + (it0 + u) * 256;
            m[u] = *(const float4*)(wre + j);
            p[u] = *(const float4*)(ph0 + j);
        }
#pragma unroll
        for (int u = 0; u < B; ++u)
            ar += m[u].x * p[u].x + m[u].y * p[u].y
                + m[u].z * p[u].z + m[u].w * p[u].w;
    }
    // pass 2: imag plane
#pragma unroll
    for (int it0 = 0; it0 < NIT; it0 += B) {
        float4 m[B], p[B];
#pragma unroll
        for (int u = 0; u < B; ++u) {
            const int j = lane * 4 + (it0 + u) * 256;
            m[u] = *(const float4*)(wim + j);
            p[u] = *(const float4*)(ph0 + j);
        }
#pragma unroll
        for (int u = 0; u < B; ++u)
            ai += m[u].x * p[u].x + m[u].y * p[u].y
                + m[u].z * p[u].z + m[u].w * p[u].w;
    }

    ar = wave_sum(ar);
    ai = wave_sum(ai);
    __shared__ float sred[16];
    if (lane == 0) { sred[w] = ar; sred[8 + w] = ai; }
    __syncthreads();
    if (threadIdx.x < 4) {
        const int r = blockIdx.x * 4 + threadIdx.x;
        ore[r] = sred[2 * threadIdx.x] + sred[2 * threadIdx.x + 1] + bias[r];
        oim[r] = sred[8 + 2 * threadIdx.x] + sred[9 + 2 * threadIdx.x] + bias[ROWS + r];
    }
}

extern "C" void kernel_launch(void* const* d_in, const int* in_sizes, int n_in,
                              void* d_out, int out_size, void* d_ws, size_t ws_size,
                              hipStream_t stream) {
    const float* x  = (const float*)d_in[0];
    const float* W1 = (const float*)d_in[1];
    const float* b1 = (const float*)d_in[2];
    const float* G1 = (const float*)d_in[3];
    const float* s1 = (const float*)d_in[4];
    const float* W2 = (const float*)d_in[5];
    const float* b2 = (const float*)d_in[6];
    const float* G2 = (const float*)d_in[7];
    const float* s2 = (const float*)d_in[8];
    const float* W3 = (const float*)d_in[9];
    const float* b3 = (const float*)d_in[10];
    const float* G3 = (const float*)d_in[11];
    const float* s3 = (const float*)d_in[12];
    float* out = (float*)d_out;   // (2, 1024)

    float* ws  = (float*)d_ws;
    float* phi = ws;              // 4096
    float* yre = ws + H;          // 4096
    float* yim = ws + 2 * H;      // 4096
    // no init needed: phi/y fully written before first read each call

    // Layer 1
    phi_k<D0, H><<<H / 4, 512, 0, stream>>>(G1, x, x + D0, s1, phi);
    w_k<H, H><<<H / 4, 512, 0, stream>>>(W1, b1, phi, yre, yim);
    // Layer 2
    phi_k<H, H><<<H / 4, 512, 0, stream>>>(G2, yre, yim, s2, phi);
    w_k<H, H><<<H / 4, 512, 0, stream>>>(W2, b2, phi, yre, yim);
    // Layer 3
    phi_k<H, H><<<H / 4, 512, 0, stream>>>(G3, yre, yim, s3, phi);
    w_k<H, D0><<<D0 / 4, 512, 0, stream>>>(W3, b3, phi, out, out + D0);
}

// Round 8
// 118.216 us; speedup vs baseline: 1.3204x; 1.3204x over previous
//
#include <hip/hip_runtime.h>

// DeepComplexRBF as 6 plain kernels in the captured graph (one per phase).
//   dist_sq[i] = sum_j |y[j] - G[i,j]|^2 ; phi[i] = exp(-dist_sq/(2 s[i]))
//   y_new[o]   = sum_i W[o,i]*phi[i] + b[o]
// 576 MB of G/W streamed once; ~half served by L3 across graph replays.
//
// r6 = 119.3 us (wave-per-row, B=4, 4 live arrays, 16 waves/CU).
// r7 = 156.1 us REGRESSION: launch_bounds(512,8) -> VGPR 32 -> ILP dead.
// r8: keep r6 structure, deepen per-wave MLP instead of adding waves:
//   two passes per row (re plane then im plane) so only 2 arrays live,
//   burst B=8 -> 16 outstanding float4 loads/wave (~8 KB/CU in flight,
//   2x r6). launch_bounds(256,4) caps VGPR at 128: fits 64 data regs +
//   addressing, cannot repeat r7's strangulation. y/phi re-reads are
//   L1-served (16-32 KB, hot).

#define D0 1024
#define H  4096

__device__ __forceinline__ float wave_sum(float v) {
#pragma unroll
    for (int off = 32; off > 0; off >>= 1) v += __shfl_down(v, off, 64);
    return v;
}

// One wave per row: phi[row] = exp(-|y - G[row]|^2 / (2 s[row])).
// G is (2, ROWS, COLS); y as separate re/im pointers. Grid: ROWS/4 x 256.
template <int COLS, int ROWS>
__global__ __launch_bounds__(256, 4) void phi_k(
        const float* __restrict__ G,
        const float* __restrict__ yre, const float* __restrict__ yim,
        const float* __restrict__ sv, float* __restrict__ phi) {
    const int lane = threadIdx.x & 63;
    const int row = (blockIdx.x * 256 + threadIdx.x) >> 6;
    const float* gre = G + (size_t)row * COLS;
    const float* gim = gre + (size_t)ROWS * COLS;

    constexpr int NIT = COLS / 256;            // float4 steps per lane (4|16)
    constexpr int B = (NIT < 8) ? NIT : 8;     // burst width

    float acc = 0.f;
#pragma unroll
    for (int pl = 0; pl < 2; ++pl) {           // pass 0: re plane, 1: im plane
        const float* gp = pl ? gim : gre;
        const float* yp = pl ? yim : yre;
#pragma unroll
        for (int it0 = 0; it0 < NIT; it0 += B) {
            float4 g[B], y[B];
#pragma unroll
            for (int u = 0; u < B; ++u) {
                const int j = lane * 4 + (it0 + u) * 256;
                g[u] = *(const float4*)(gp + j);
                y[u] = *(const float4*)(yp + j);
            }
#pragma unroll
            for (int u = 0; u < B; ++u) {
                float d;
                d = y[u].x - g[u].x; acc += d * d;
                d = y[u].y - g[u].y; acc += d * d;
                d = y[u].z - g[u].z; acc += d * d;
                d = y[u].w - g[u].w; acc += d * d;
            }
        }
    }
    acc = wave_sum(acc);
    if (lane == 0) phi[row] = expf(-acc / (2.0f * sv[row]));
}

// One wave per row: (ore,oim)[row] = W[row] . phi + b[row].
// W is (2, ROWS, COLS); bias is (2, ROWS) flat. Grid: ROWS/4 x 256.
template <int COLS, int ROWS>
__global__ __launch_bounds__(256, 4) void w_k(
        const float* __restrict__ W, const float* __restrict__ bias,
        const float* __restrict__ phi,
        float* __restrict__ ore, float* __restrict__ oim) {
    const int lane = threadIdx.x & 63;
    const int row = (blockIdx.x * 256 + threadIdx.x) >> 6;
    const float* wre = W + (size_t)row * COLS;
    const float* wim = wre + (size_t)ROWS * COLS;

    constexpr int NIT = COLS / 256;            // 16
    constexpr int B = (NIT < 8) ? NIT : 8;

    float ac[2] = {0.f, 0.f};
#pragma unroll
    for (int pl = 0; pl < 2; ++pl) {           // pass 0: re plane, 1: im plane
        const float* mp = pl ? wim : wre;
        float a = 0.f;
#pragma unroll
        for (int it0 = 0; it0 < NIT; it0 += B) {
            float4 m[B], p[B];
#pragma unroll
            for (int u = 0; u < B; ++u) {
                const int j = lane * 4 + (it0 + u) * 256;
                m[u] = *(const float4*)(mp + j);
                p[u] = *(const float4*)(phi + j);
            }
#pragma unroll
            for (int u = 0; u < B; ++u)
                a += m[u].x * p[u].x + m[u].y * p[u].y
                   + m[u].z * p[u].z + m[u].w * p[u].w;
        }
        ac[pl] = a;
    }
    const float ar = wave_sum(ac[0]);
    const float ai = wave_sum(ac[1]);
    if (lane == 0) {
        ore[row] = ar + bias[row];
        oim[row] = ai + bias[ROWS + row];
    }
}

extern "C" void kernel_launch(void* const* d_in, const int* in_sizes, int n_in,
                              void* d_out, int out_size, void* d_ws, size_t ws_size,
                              hipStream_t stream) {
    const float* x  = (const float*)d_in[0];
    const float* W1 = (const float*)d_in[1];
    const float* b1 = (const float*)d_in[2];
    const float* G1 = (const float*)d_in[3];
    const float* s1 = (const float*)d_in[4];
    const float* W2 = (const float*)d_in[5];
    const float* b2 = (const float*)d_in[6];
    const float* G2 = (const float*)d_in[7];
    const float* s2 = (const float*)d_in[8];
    const float* W3 = (const float*)d_in[9];
    const float* b3 = (const float*)d_in[10];
    const float* G3 = (const float*)d_in[11];
    const float* s3 = (const float*)d_in[12];
    float* out = (float*)d_out;   // (2, 1024)

    float* ws  = (float*)d_ws;
    float* phi = ws;              // 4096
    float* yre = ws + H;          // 4096
    float* yim = ws + 2 * H;      // 4096
    // no init needed: phi/y fully written before first read each call

    // Layer 1
    phi_k<D0, H><<<H / 4, 256, 0, stream>>>(G1, x, x + D0, s1, phi);
    w_k<H, H><<<H / 4, 256, 0, stream>>>(W1, b1, phi, yre, yim);
    // Layer 2
    phi_k<H, H><<<H / 4, 256, 0, stream>>>(G2, yre, yim, s2, phi);
    w_k<H, H><<<H / 4, 256, 0, stream>>>(W2, b2, phi, yre, yim);
    // Layer 3
    phi_k<H, H><<<H / 4, 256, 0, stream>>>(G3, yre, yim, s3, phi);
    w_k<H, D0><<<D0 / 4, 256, 0, stream>>>(W3, b3, phi, out, out + D0);
}